// Round 13
// baseline (46.748 us; speedup 1.0000x reference)
//
#include <hip/hip_runtime.h>

// G=16, H=8, N=128/side, HD=32, D=256
// x tensors: row-major [2048][256] f32; head (g,h) chunk = flat gh*4096, node-major [128][32].
#define LOG2E 1.4426950408889634f

// ws float offsets
#define WS_X1   0          // [2048][256] f32 x1 (raw)
#define WS_X2   524288     // [2048][256] f32 x2
#define WS_RS   1572864    // [gh][128] row sums
#define WS_CQ   1589248    // [gh*4+qd][128] col quarter partials
// bf16 hi/lo staging in MFMA-fragment order [tile][kt][lane][8] (ushort arrays)
#define WS_AH   1703936
#define WS_AL   1966080
#define WS_BH   2228224
#define WS_BL   2490368
#define WS_W1H  2752512
#define WS_W1L  2785280
#define WS_W2H  2818048
#define WS_W2L  2850816

typedef short bf16x8 __attribute__((ext_vector_type(8)));
typedef float f32x4 __attribute__((ext_vector_type(4)));

__device__ __forceinline__ unsigned short bf16rne(float f) {
    unsigned u = __float_as_uint(f);
    u += 0x7FFF + ((u >> 16) & 1);
    return (unsigned short)(u >> 16);
}
__device__ __forceinline__ float bf16tof(unsigned short h) {
    return __uint_as_float(((unsigned)h) << 16);
}
// bit-preserving wave-uniform scalar broadcast (readfirstlane is int-typed!)
__device__ __forceinline__ float rfl(float x) {
    return __uint_as_float(__builtin_amdgcn_readfirstlane(__float_as_uint(x)));
}

// ================= K0: fp32 -> bf16 hi/lo split, MFMA-fragment layout (verified) =================
__global__ __launch_bounds__(256) void k0_convert(
        const float* __restrict__ A, const float* __restrict__ B,
        const float* __restrict__ W1, const float* __restrict__ W2,
        float* __restrict__ ws) {
    const int t = blockIdx.x * 256 + threadIdx.x;
    const float* src; unsigned short *dh, *dl; int tl;
    if (t < 65536)       { src = A;  dh = (unsigned short*)(ws + WS_AH);  dl = (unsigned short*)(ws + WS_AL);  tl = t; }
    else if (t < 131072) { src = B;  dh = (unsigned short*)(ws + WS_BH);  dl = (unsigned short*)(ws + WS_BL);  tl = t - 65536; }
    else if (t < 139264) { src = W1; dh = (unsigned short*)(ws + WS_W1H); dl = (unsigned short*)(ws + WS_W1L); tl = t - 131072; }
    else                 { src = W2; dh = (unsigned short*)(ws + WS_W2H); dl = (unsigned short*)(ws + WS_W2L); tl = t - 139264; }
    const int lane = tl & 63, kt = (tl >> 6) & 7, rt = tl >> 9;
    const int row = rt * 16 + (lane & 15);
    const int col = kt * 32 + (lane >> 4) * 8;
    float4 v0 = *(const float4*)(src + (size_t)row * 256 + col);
    float4 v1 = *(const float4*)(src + (size_t)row * 256 + col + 4);
    ushort4 h0, h1, l0, l1;
    h0.x = bf16rne(v0.x); l0.x = bf16rne(v0.x - bf16tof(h0.x));
    h0.y = bf16rne(v0.y); l0.y = bf16rne(v0.y - bf16tof(h0.y));
    h0.z = bf16rne(v0.z); l0.z = bf16rne(v0.z - bf16tof(h0.z));
    h0.w = bf16rne(v0.w); l0.w = bf16rne(v0.w - bf16tof(h0.w));
    h1.x = bf16rne(v1.x); l1.x = bf16rne(v1.x - bf16tof(h1.x));
    h1.y = bf16rne(v1.y); l1.y = bf16rne(v1.y - bf16tof(h1.y));
    h1.z = bf16rne(v1.z); l1.z = bf16rne(v1.z - bf16tof(h1.z));
    h1.w = bf16rne(v1.w); l1.w = bf16rne(v1.w - bf16tof(h1.w));
    ((ushort4*)dh)[tl * 2]     = h0;
    ((ushort4*)dh)[tl * 2 + 1] = h1;
    ((ushort4*)dl)[tl * 2]     = l0;
    ((ushort4*)dl)[tl * 2 + 1] = l1;
}

// ================= K1: split-bf16 MFMA GEMM x = In @ W^T + bias (verified; x1s pass removed) =================
__global__ __launch_bounds__(256) void k1_mfma(
        const float* __restrict__ b1, const float* __restrict__ b2,
        float* __restrict__ ws) {
    const int bid = blockIdx.x, tid = threadIdx.x;
    const int mat = bid >> 7, idx = bid & 127;
    const int r0 = (idx >> 2) * 64, c0 = (idx & 3) * 64;
    const unsigned short* IH  = (const unsigned short*)(ws + (mat ? WS_BH : WS_AH));
    const unsigned short* IL  = (const unsigned short*)(ws + (mat ? WS_BL : WS_AL));
    const unsigned short* WHp = (const unsigned short*)(ws + (mat ? WS_W2H : WS_W1H));
    const unsigned short* WLp = (const unsigned short*)(ws + (mat ? WS_W2L : WS_W1L));
    const float* bs = mat ? b2 : b1;
    float* xo = ws + (mat ? WS_X2 : WS_X1);

    const int wv = tid >> 6, lane = tid & 63;
    const int rt = (idx >> 2) * 4 + wv;
    const int ct0 = (idx & 3) * 4;

    f32x4 acc[4];
    #pragma unroll
    for (int nt = 0; nt < 4; ++nt) acc[nt] = (f32x4){0.f, 0.f, 0.f, 0.f};

    for (int kt = 0; kt < 8; ++kt) {
        bf16x8 ah = *(const bf16x8*)(IH + ((size_t)(rt * 8 + kt) * 64 + lane) * 8);
        bf16x8 al = *(const bf16x8*)(IL + ((size_t)(rt * 8 + kt) * 64 + lane) * 8);
        #pragma unroll
        for (int nt = 0; nt < 4; ++nt) {
            const int ct = ct0 + nt;
            bf16x8 wh = *(const bf16x8*)(WHp + ((size_t)(ct * 8 + kt) * 64 + lane) * 8);
            bf16x8 wl = *(const bf16x8*)(WLp + ((size_t)(ct * 8 + kt) * 64 + lane) * 8);
            acc[nt] = __builtin_amdgcn_mfma_f32_16x16x32_bf16(ah, wh, acc[nt], 0, 0, 0);
            acc[nt] = __builtin_amdgcn_mfma_f32_16x16x32_bf16(ah, wl, acc[nt], 0, 0, 0);
            acc[nt] = __builtin_amdgcn_mfma_f32_16x16x32_bf16(al, wh, acc[nt], 0, 0, 0);
        }
    }

    const int rowb = r0 + wv * 16 + (lane >> 4) * 4;
    const int l16 = lane & 15;
    #pragma unroll
    for (int nt = 0; nt < 4; ++nt) {
        const int col = c0 + nt * 16 + l16;
        const float bb = bs[col];
        #pragma unroll
        for (int rg = 0; rg < 4; ++rg)
            xo[(size_t)(rowb + rg) * 256 + col] = acc[nt][rg] + bb;
    }
}

// ================= K2: att logits via Padé(7,6) tanh — 1 transcendental per pair =================
// S(i,j) = sum_k q_k * tanh(x1_ik * x2_jk), tanh(p) = p*N(u)/D(u), u = p^2 (CF truncation):
// N = 135135 + 17325u + 378u^2 + u^3 ; D = 135135 + 62370u + 3150u^2 + 28u^3. Clamp |p|<=6.
// Pair-shared reciprocal: q0*t0 + q1*t1 = (w0*n0*d1 + w1*n1*d0) * rcp(d0*d1).
// Structure identical to the verified r12 kernel (SGPR a/qt via bit-preserving rfl).
__global__ __launch_bounds__(512, 6) void k2_att(
        const float* __restrict__ x1v, const float* __restrict__ x2v,
        const float* __restrict__ q,
        float* __restrict__ rowsum, float* __restrict__ colq) {
    const int bid = blockIdx.x;
    const int gh = bid >> 2;
    const int qd = bid & 3;
    const int tid = threadIdx.x;
    const int j = tid & 127;
    const int iset = __builtin_amdgcn_readfirstlane(tid >> 7);  // wave-uniform 0..3

    __shared__ float Smat[32 * 132];
    __shared__ float colp[4][128];
    __shared__ float red8[32][8];

    // x2 row j -> VGPRs (per-lane)
    float xr[32];
    {
        const float4* xp = (const float4*)(x2v + (size_t)gh * 4096 + (size_t)j * 32);
        #pragma unroll
        for (int k4 = 0; k4 < 8; ++k4) {
            float4 v = xp[k4];
            xr[k4*4+0] = v.x; xr[k4*4+1] = v.y; xr[k4*4+2] = v.z; xr[k4*4+3] = v.w;
        }
    }
    // qt = q -> SGPRs (bit-preserving broadcast)
    float qt[32];
    #pragma unroll
    for (int k4 = 0; k4 < 8; ++k4) {
        float4 v = *(const float4*)(q + k4 * 4);
        qt[k4*4+0] = rfl(v.x);
        qt[k4*4+1] = rfl(v.y);
        qt[k4*4+2] = rfl(v.z);
        qt[k4*4+3] = rfl(v.w);
    }

    const float* x1base = x1v + (size_t)gh * 4096 + (size_t)(qd * 32 + iset * 8) * 32;
    float colacc = 0.f;

    for (int r = 0; r < 8; ++r) {
        float a[32];                                   // wave-uniform -> SGPRs
        #pragma unroll
        for (int k4 = 0; k4 < 8; ++k4) {
            float4 v = *(const float4*)(x1base + r * 32 + k4 * 4);
            a[k4*4+0] = rfl(v.x);
            a[k4*4+1] = rfl(v.y);
            a[k4*4+2] = rfl(v.z);
            a[k4*4+3] = rfl(v.w);
        }
        float S0 = 0.f, S1 = 0.f;
        #pragma unroll
        for (int kp = 0; kp < 16; ++kp) {
            float p0 = a[2*kp]   * xr[2*kp];
            float p1 = a[2*kp+1] * xr[2*kp+1];
            p0 = fminf(fmaxf(p0, -6.f), 6.f);
            p1 = fminf(fmaxf(p1, -6.f), 6.f);
            float u0 = p0 * p0, u1 = p1 * p1;
            float n0 = fmaf(fmaf(u0 + 378.f, u0, 17325.f), u0, 135135.f);
            float n1 = fmaf(fmaf(u1 + 378.f, u1, 17325.f), u1, 135135.f);
            float d0 = fmaf(fmaf(fmaf(u0, 28.f, 3150.f), u0, 62370.f), u0, 135135.f);
            float d1 = fmaf(fmaf(fmaf(u1, 28.f, 3150.f), u1, 62370.f), u1, 135135.f);
            float w0 = qt[2*kp]   * p0;
            float w1 = qt[2*kp+1] * p1;
            float rD = __builtin_amdgcn_rcpf(d0 * d1);
            float U  = fmaf(w1 * n1, d0, (w0 * n0) * d1);
            if (kp & 1) S1 = fmaf(U, rD, S1); else S0 = fmaf(U, rD, S0);
        }
        float S = S0 + S1;
        colacc += S;
        Smat[(iset * 8 + r) * 132 + j] = S;
    }
    colp[iset][j] = colacc;
    __syncthreads();

    if (tid < 256) {                       // rowsum stage 1: 16-chunk sums
        const int row = tid >> 3, seg = tid & 7;
        const float4* sp = (const float4*)(Smat + row * 132 + seg * 16);
        float4 v0 = sp[0], v1 = sp[1], v2 = sp[2], v3 = sp[3];
        red8[row][seg] = (v0.x+v0.y+v0.z+v0.w) + (v1.x+v1.y+v1.z+v1.w)
                       + (v2.x+v2.y+v2.z+v2.w) + (v3.x+v3.y+v3.z+v3.w);
    }
    __syncthreads();
    if (tid < 32) {
        float s = 0.f;
        #pragma unroll
        for (int m = 0; m < 8; ++m) s += red8[tid][m];
        rowsum[gh * 128 + qd * 32 + tid] = s;
    }
    if (tid < 128) {
        colq[(size_t)bid * 128 + tid] =
            colp[0][tid] + colp[1][tid] + colp[2][tid] + colp[3][tid];
    }
}

// ================= K3: softmaxes + weighted sums -> out (verified) =================
__global__ __launch_bounds__(256) void k3_out(
        const float* __restrict__ x1v, const float* __restrict__ x2v,
        const float* __restrict__ rowsum, const float* __restrict__ colq,
        float* __restrict__ out) {
    const int gh = blockIdx.x;
    const int g = gh >> 3, h = gh & 7;
    const int tid = threadIdx.x;
    const int side = tid >> 7;
    const int u = tid & 127;
    const int w2 = (u >> 6) & 1;
    const int lane = tid & 63;

    __shared__ float warr[2][128];
    __shared__ float red[4];
    __shared__ float red2[4];
    __shared__ float part[2][4][32];

    float m;
    if (side == 0) {
        m = rowsum[gh * 128 + u] * 0.0078125f;
    } else {
        m = (colq[(size_t)(gh * 4 + 0) * 128 + u] + colq[(size_t)(gh * 4 + 1) * 128 + u] +
             colq[(size_t)(gh * 4 + 2) * 128 + u] + colq[(size_t)(gh * 4 + 3) * 128 + u]) * 0.0078125f;
    }

    float mx = m;
    #pragma unroll
    for (int s = 32; s >= 1; s >>= 1) mx = fmaxf(mx, __shfl_xor(mx, s));
    if (lane == 0) red[side * 2 + w2] = mx;
    __syncthreads();
    mx = fmaxf(red[side * 2], red[side * 2 + 1]);

    float e = __builtin_amdgcn_exp2f((m - mx) * LOG2E);
    float sm = e;
    #pragma unroll
    for (int s = 32; s >= 1; s >>= 1) sm += __shfl_xor(sm, s);
    if (lane == 0) red2[side * 2 + w2] = sm;
    __syncthreads();
    const float tot = red2[side * 2] + red2[side * 2 + 1];
    warr[side][u] = e * __builtin_amdgcn_rcpf(tot);
    __syncthreads();

    const int k = u & 31, is = u >> 5;
    const float* xt = (side ? x2v : x1v) + (size_t)gh * 4096;
    float p = 0.f;
    #pragma unroll 4
    for (int r = 0; r < 32; ++r)
        p = fmaf(xt[(is * 32 + r) * 32 + k], warr[side][is * 32 + r], p);
    part[side][is][k] = p;
    __syncthreads();
    if (u < 32) {
        float o = part[side][0][u] + part[side][1][u] + part[side][2][u] + part[side][3][u];
        out[(size_t)g * 512 + side * 256 + h * 32 + u] = o;
    }
}

extern "C" void kernel_launch(void* const* d_in, const int* in_sizes, int n_in,
                              void* d_out, int out_size, void* d_ws, size_t ws_size,
                              hipStream_t stream) {
    const float* A  = (const float*)d_in[0];
    const float* B  = (const float*)d_in[2];
    const float* W1 = (const float*)d_in[4];
    const float* b1 = (const float*)d_in[5];
    const float* W2 = (const float*)d_in[6];
    const float* b2 = (const float*)d_in[7];
    const float* q  = (const float*)d_in[8];
    float* ws  = (float*)d_ws;
    float* out = (float*)d_out;

    k0_convert<<<576, 256, 0, stream>>>(A, B, W1, W2, ws);
    k1_mfma<<<256, 256, 0, stream>>>(b1, b2, ws);
    k2_att<<<512, 512, 0, stream>>>(ws + WS_X1, ws + WS_X2, q, ws + WS_RS, ws + WS_CQ);
    k3_out<<<128, 256, 0, stream>>>(ws + WS_X1, ws + WS_X2, ws + WS_RS, ws + WS_CQ, out);
}